// Round 20
// baseline (378.436 us; speedup 1.0000x reference)
//
#include <hip/hip_runtime.h>
#include <math.h>

#define SELU_ALPHA 1.6732632423543772f
#define SELU_SCALE 1.0507009873554805f

#define NBLK 512          // partition blocks (E divides exactly: 512*3125)
#define MAXBKT 512        // static LDS sizing; actual NBKT = ceil(N/256)

typedef __attribute__((ext_vector_type(8))) short bf16x8;
typedef __attribute__((ext_vector_type(4))) float f32x4;

__device__ __forceinline__ float selu_f(float x) {
    return SELU_SCALE * (x > 0.f ? x : SELU_ALPHA * expm1f(x));
}

__device__ __forceinline__ float bf2f(unsigned short u) {
    return __uint_as_float(((unsigned)u) << 16);
}
__device__ __forceinline__ unsigned short f2bf(float f) {
    unsigned u = __float_as_uint(f);
    unsigned r = (u + 0x7fffu + ((u >> 16) & 1u)) >> 16;
    return (unsigned short)r;
}

// ---- scan stage 1 ----
#define SCAN_B 1024

__global__ __launch_bounds__(256) void scan_block_sums(const int* __restrict__ in,
                                                       int* __restrict__ bsums, int n) {
    __shared__ int s[256];
    int b = blockIdx.x, t = threadIdx.x;
    int base = b * SCAN_B;
    int sum = 0;
    for (int i = t; i < SCAN_B; i += 256) {
        int idx = base + i;
        sum += (idx < n) ? in[idx] : 0;
    }
    s[t] = sum; __syncthreads();
    for (int off = 128; off > 0; off >>= 1) {
        if (t < off) s[t] += s[t + off];
        __syncthreads();
    }
    if (t == 0) bsums[b] = s[0];
}

// ---- scan stage 2 (fused bsums-scan + apply), in-place safe ----
__global__ __launch_bounds__(256) void scan_apply2(const int* __restrict__ in,
                                                   const int* __restrict__ bsums,
                                                   int* __restrict__ out, int n, int nb) {
    __shared__ int sb[512];
    __shared__ int s[256];
    __shared__ int blockoff;
    int b = blockIdx.x, t = threadIdx.x;

    int orig0 = (t < nb) ? bsums[t] : 0;
    int orig1 = (t + 256 < nb) ? bsums[t + 256] : 0;
    sb[t] = orig0; sb[t + 256] = orig1;
    __syncthreads();
    for (int off = 1; off < 512; off <<= 1) {
        int v0 = (t >= off) ? sb[t - off] : 0;
        int v1 = (t + 256 >= off) ? sb[t + 256 - off] : 0;
        __syncthreads();
        sb[t] += v0; sb[t + 256] += v1;
        __syncthreads();
    }
    if (t == (b & 255)) {
        bool hi = b >= 256;
        int incl = hi ? sb[t + 256] : sb[t];
        int orig = hi ? orig1 : orig0;
        blockoff = incl - orig;
    }
    __syncthreads();

    int idx0 = b * SCAN_B + t * 4;
    int v[4]; int tsum = 0;
    #pragma unroll
    for (int k = 0; k < 4; ++k) {
        int idx = idx0 + k;
        v[k] = (idx < n) ? in[idx] : 0;
        tsum += v[k];
    }
    s[t] = tsum; __syncthreads();
    for (int off = 1; off < 256; off <<= 1) {
        int x = (t >= off) ? s[t - off] : 0;
        __syncthreads();
        s[t] += x;
        __syncthreads();
    }
    int run = s[t] - tsum + blockoff;
    #pragma unroll
    for (int k = 0; k < 4; ++k) {
        int idx = idx0 + k;
        if (idx < n) out[idx] = run;
        run += v[k];
    }
}

// ---- K1 (merged): blocks [0,NBLK) = coarse histograms; rest = weight prep.
//      Head weights TRANSPOSED for vectorized loads:
//      W1cT[256][136] = [W3@L1wA ; L1w rows 128-130 ; b3@L1wA ; 0-pad]^T
//      L2wT[128][256] = L2w^T ----
__global__ __launch_bounds__(256) void hist_prep_kernel(
        const int* __restrict__ src, const int* __restrict__ dst,
        int* __restrict__ cntD, int* __restrict__ cntS, int E, int nbkt,
        const float* __restrict__ W1, const float* __restrict__ W2,
        const float* __restrict__ W3, const float* __restrict__ b3,
        const float* __restrict__ L1w, const float* __restrict__ L2w,
        unsigned short* __restrict__ Wt1, unsigned short* __restrict__ Wt2,
        unsigned short* __restrict__ W1cT, unsigned short* __restrict__ L2wT) {
    if (blockIdx.x >= NBLK) {
        const int s0 = 128 * 64;        // Wt1
        const int s1 = 128 * 128;       // Wt2
        const int s2 = 128 * 256;       // M = W3 @ L1wA -> W1cT[o][k]
        const int s3 = 3 * 256;         // L1w rows 128-130 -> W1cT[o][128+r]
        const int s4 = 256;             // c3 = b3 @ L1wA -> W1cT[o][131]
        const int s6 = 4 * 256;         // zero pad -> W1cT[o][132..135]
        const int s5 = 128 * 256;       // L2wT[o][k]
        int i = (blockIdx.x - NBLK) * 256 + threadIdx.x;
        if (i < s0) { int col = i / 64, k = i % 64; Wt1[i] = f2bf(W1[k * 128 + col]); return; }
        i -= s0;
        if (i < s1) { int col = i / 128, k = i % 128; Wt2[i] = f2bf(W2[k * 128 + col]); return; }
        i -= s1;
        if (i < s2) {
            int k = i >> 8, o = i & 255;
            float acc = 0.f;
            #pragma unroll 8
            for (int m = 0; m < 128; ++m)
                acc += W3[k * 128 + m] * L1w[m * 256 + o];
            W1cT[o * 136 + k] = f2bf(acc);
            return;
        }
        i -= s2;
        if (i < s3) {
            int r = i >> 8, o = i & 255;
            W1cT[o * 136 + 128 + r] = f2bf(L1w[(128 + r) * 256 + o]);
            return;
        }
        i -= s3;
        if (i < s4) {
            int o = i;
            float acc = 0.f;
            #pragma unroll 8
            for (int m = 0; m < 128; ++m)
                acc += b3[m] * L1w[m * 256 + o];
            W1cT[o * 136 + 131] = f2bf(acc);
            return;
        }
        i -= s4;
        if (i < s6) {
            int p = i >> 8, o = i & 255;
            W1cT[o * 136 + 132 + p] = 0;
            return;
        }
        i -= s6;
        if (i < s5) {
            int o = i >> 8, k = i & 255;
            L2wT[o * 256 + k] = f2bf(L2w[k * 128 + o]);
        }
        return;
    }
    __shared__ int hD[MAXBKT];
    __shared__ int hS[MAXBKT];
    int bb = blockIdx.x, t = threadIdx.x;
    for (int k = t; k < MAXBKT; k += 256) { hD[k] = 0; hS[k] = 0; }
    __syncthreads();
    int chunk = E / NBLK;
    int beg = bb * chunk, end = beg + chunk;
    for (int i = beg + t; i < end; i += 256) {
        atomicAdd(&hD[((unsigned)dst[i]) >> 8], 1);
        atomicAdd(&hS[((unsigned)src[i]) >> 8], 1);
    }
    __syncthreads();
    for (int k = t; k < nbkt; k += 256) {
        cntD[k * NBLK + bb] = hD[k];
        cntS[k * NBLK + bb] = hS[k];
    }
}

// ---- K2: scatter. pairs packed u32: src | (dst&255)<<24 (needs N < 2^24). ----
__global__ __launch_bounds__(256) void scatter_kernel(
        const int* __restrict__ src, const int* __restrict__ dst,
        const int* __restrict__ cntD, const int* __restrict__ cntS,
        unsigned* __restrict__ pairs, int* __restrict__ sbufm, int E, int nbkt) {
    __shared__ int cD[MAXBKT];
    __shared__ int cS[MAXBKT];
    int bb = blockIdx.x, t = threadIdx.x;
    for (int k = t; k < nbkt; k += 256) {
        cD[k] = cntD[k * NBLK + bb];
        cS[k] = cntS[k * NBLK + bb];
    }
    __syncthreads();
    int chunk = E / NBLK;
    int beg = bb * chunk, end = beg + chunk;
    for (int i = beg + t; i < end; i += 256) {
        unsigned s = (unsigned)src[i], d = (unsigned)dst[i];
        int pD = atomicAdd(&cD[d >> 8], 1);
        pairs[pD] = s | ((d & 255u) << 24);
        int pS = atomicAdd(&cS[s >> 8], 1);
        sbufm[pS] = (int)s;
    }
}

// ---- K3: fused bucket build + feature conversion ----
__global__ __launch_bounds__(256) void bucket_build_kernel(
        const int* __restrict__ sbufm, const unsigned* __restrict__ pairs,
        const int* __restrict__ cntD, const int* __restrict__ cntS,
        const float* __restrict__ feats,
        float* __restrict__ norm_out, unsigned short* __restrict__ feats16,
        int* __restrict__ row_start, int* __restrict__ deg_in,
        int* __restrict__ csr_src, int N, int E, int nbkt) {
    __shared__ int hist[256];
    __shared__ int sc[256];
    __shared__ int cur[256];
    __shared__ float nrm[256];
    int b = blockIdx.x, t = threadIdx.x;
    int node = (b << 8) + t;
    int node0 = b << 8;

    // part 1: deg_out histogram from src-bucket values (+E offset indices)
    {
        int base = cntS[b * NBLK];
        int end = (b + 1 < nbkt) ? cntS[(b + 1) * NBLK] : 2 * E;
        hist[t] = 0; __syncthreads();
        for (int i = base + t; i < end; i += 256)
            atomicAdd(&hist[sbufm[i] & 255], 1);
        __syncthreads();
        float no = 1.f / sqrtf(fmaxf((float)hist[t], 1.f));
        nrm[t] = no;
        if (node < N) norm_out[node] = no;
        __syncthreads();
    }

    // part 1b: convert this node range's features to bf16, prescaled by norm_out
    {
        int cnt = min(256, N - node0);
        for (int i = t; i < cnt * 8; i += 256) {
            int nl = i >> 3, c = i & 7;
            float no = nrm[nl];
            const float* fp = feats + (size_t)(node0 + nl) * 64 + c * 8;
            float4 a = *reinterpret_cast<const float4*>(fp);
            float4 bv = *reinterpret_cast<const float4*>(fp + 4);
            unsigned short o[8] = { f2bf(a.x * no), f2bf(a.y * no), f2bf(a.z * no), f2bf(a.w * no),
                                    f2bf(bv.x * no), f2bf(bv.y * no), f2bf(bv.z * no), f2bf(bv.w * no) };
            *reinterpret_cast<float4*>(feats16 + (size_t)(node0 + nl) * 64 + c * 8) =
                *reinterpret_cast<float4*>(o);
        }
        __syncthreads();
    }

    // part 2: CSR build from packed dst-bucket pairs
    {
        int base = cntD[b * NBLK];
        int end = (b + 1 < nbkt) ? cntD[(b + 1) * NBLK] : E;
        hist[t] = 0; __syncthreads();
        for (int i = base + t; i < end; i += 256)
            atomicAdd(&hist[(pairs[i] >> 24) & 255], 1);
        __syncthreads();
        int v = hist[t];
        sc[t] = v; __syncthreads();
        for (int off = 1; off < 256; off <<= 1) {
            int x = (t >= off) ? sc[t - off] : 0;
            __syncthreads();
            sc[t] += x;
            __syncthreads();
        }
        int ex = sc[t] - v;
        cur[t] = base + ex;
        if (node < N) { row_start[node] = base + ex; deg_in[node] = v; }
        __syncthreads();
        for (int i = base + t; i < end; i += 256) {
            unsigned p = pairs[i];
            int pos = atomicAdd(&cur[(p >> 24) & 255], 1);
            csr_src[pos] = (int)(p & 0xFFFFFFu);
        }
    }
}

// ---- gather-aggregate with shuffle-broadcast + next-chunk index prefetch ----
template<int TPG, int FIN>   // TPG = FIN/8
__global__ __launch_bounds__(256) void csr_agg_kernel(
        const unsigned short* __restrict__ x, const int* __restrict__ row_start,
        const int* __restrict__ deg_in, const int* __restrict__ csr_src,
        unsigned short* __restrict__ agg, int N) {
    const int GPB = 256 / TPG;
    int g = threadIdx.x / TPG;
    int j = threadIdx.x % TPG;
    int n = blockIdx.x * GPB + g;
    if (n >= N) return;
    const int lane = threadIdx.x & 63;
    const int gbase = lane & ~(TPG - 1);
    int beg = row_start[n];
    int dg = deg_in[n];
    int end = beg + dg;
    float nin = 1.f / sqrtf(fmaxf((float)dg, 1.f));
    float acc[8] = {0.f, 0.f, 0.f, 0.f, 0.f, 0.f, 0.f, 0.f};
    int myIdx = (beg + j < end) ? csr_src[beg + j] : 0;
    for (int c = beg; c < end; c += TPG) {
        int cnt = end - c;
        int nxtIdx = (c + TPG + j < end) ? csr_src[c + TPG + j] : 0;
        float4 v[TPG];
        #pragma unroll
        for (int t = 0; t < TPG; ++t) {
            if (t < cnt) {
                int s = __shfl(myIdx, gbase + t, 64);
                v[t] = *reinterpret_cast<const float4*>(&x[(size_t)s * FIN + j * 8]);
            }
        }
        #pragma unroll
        for (int t = 0; t < TPG; ++t) {
            if (t < cnt) {
                const unsigned short* u = reinterpret_cast<const unsigned short*>(&v[t]);
                #pragma unroll
                for (int k = 0; k < 8; ++k) acc[k] += bf2f(u[k]);
            }
        }
        myIdx = nxtIdx;
    }
    unsigned short ov[8];
    #pragma unroll
    for (int k = 0; k < 8; ++k) ov[k] = f2bf(acc[k] * nin);
    *reinterpret_cast<float4*>(&agg[(size_t)n * FIN + j * 8]) = *reinterpret_cast<float4*>(ov);
}

// ---- MFMA node GEMM: W in LDS only (4 blocks/CU), A streamed from global ----
template<int FIN, bool SELU, bool SCALE_OUT>
__global__ __launch_bounds__(256, 4) void gemm_mfma_kernel(
        const unsigned short* __restrict__ agg16,  // [N][FIN] bf16
        const unsigned short* __restrict__ Wt,     // [128][FIN] bf16
        const float* __restrict__ b,
        const float* __restrict__ norm_out,
        unsigned short* __restrict__ out,          // [N][128] bf16
        int N) {
    const int PAD = 8;
    const int LDW = FIN + PAD;
    const int CH = FIN / 8;
    __shared__ unsigned short sW[128 * LDW];
    const int tid = threadIdx.x;
    const int wave = tid >> 6, lane = tid & 63;
    const int wr = (wave >> 1) * 64;
    const int wc = (wave & 1) * 64;
    const int n0 = blockIdx.x * 128;

    for (int i = tid; i < 128 * CH; i += 256) {
        int col = i / CH, kc = i % CH;
        *reinterpret_cast<float4*>(&sW[col * LDW + kc * 8]) =
            *reinterpret_cast<const float4*>(&Wt[col * FIN + kc * 8]);
    }
    __syncthreads();

    const int l16 = lane & 15;
    const int lk = (lane >> 4) * 8;
    const bf16x8 zero8 = (bf16x8){0,0,0,0,0,0,0,0};
    f32x4 acc[4][4];
    #pragma unroll
    for (int mi = 0; mi < 4; ++mi)
        #pragma unroll
        for (int ci = 0; ci < 4; ++ci)
            acc[mi][ci] = (f32x4){0.f, 0.f, 0.f, 0.f};

    #pragma unroll
    for (int k0 = 0; k0 < FIN; k0 += 32) {
        bf16x8 a[4], w[4];
        #pragma unroll
        for (int mi = 0; mi < 4; ++mi) {
            int n = n0 + wr + mi * 16 + l16;
            a[mi] = (n < N)
                ? *reinterpret_cast<const bf16x8*>(&agg16[(size_t)n * FIN + k0 + lk])
                : zero8;
        }
        #pragma unroll
        for (int ci = 0; ci < 4; ++ci)
            w[ci] = *reinterpret_cast<const bf16x8*>(&sW[(wc + ci * 16 + l16) * LDW + k0 + lk]);
        #pragma unroll
        for (int mi = 0; mi < 4; ++mi)
            #pragma unroll
            for (int ci = 0; ci < 4; ++ci)
                acc[mi][ci] = __builtin_amdgcn_mfma_f32_16x16x32_bf16(
                    a[mi], w[ci], acc[mi][ci], 0, 0, 0);
    }

    const int rbase = (lane >> 4) * 4;
    #pragma unroll
    for (int ci = 0; ci < 4; ++ci) {
        int col = wc + ci * 16 + l16;
        float bias = b[col];
        #pragma unroll
        for (int mi = 0; mi < 4; ++mi) {
            #pragma unroll
            for (int r = 0; r < 4; ++r) {
                int n = n0 + wr + mi * 16 + rbase + r;
                if (n < N) {
                    float v = acc[mi][ci][r] + bias;
                    if (SELU) v = selu_f(v);
                    if (SCALE_OUT) v *= norm_out[n];
                    out[(size_t)n * 128 + col] = f2bf(v);
                }
            }
        }
    }
}

// ---- FUSED head: one block per graph; transposed weights -> 16B vector loads ----
__global__ __launch_bounds__(256) void head_kernel(
        const unsigned short* __restrict__ agg16,  // [N][128] bf16
        const int* __restrict__ n2g,               // [N] sorted
        const float* __restrict__ fg,              // [G][3]
        const unsigned short* __restrict__ W1cT,   // [256][136] bf16 (padded)
        const float* __restrict__ L1b,
        const unsigned short* __restrict__ L2wT,   // [128][256] bf16
        const float* __restrict__ L2b,
        const float* __restrict__ L3w, const float* __restrict__ L3b,
        float* __restrict__ out, int N, int G) {
    __shared__ float sIn[136];
    __shared__ float sY1[256];
    __shared__ float sPair[256];
    __shared__ float sRed[2];
    int g = blockIdx.x;
    if (g >= G) return;
    int tid = threadIdx.x;

    // boundaries (each thread; cheap)
    int beg, end;
    {
        int lo = 0, hi = N;
        while (lo < hi) { int m = (lo + hi) >> 1; if (n2g[m] < g) lo = m + 1; else hi = m; }
        beg = lo;
        lo = beg; hi = N;
        while (lo < hi) { int m = (lo + hi) >> 1; if (n2g[m] < g + 1) lo = m + 1; else hi = m; }
        end = lo;
    }

    // phase 0: readout (2 threads/col)
    {
        int col = tid & 127, h = tid >> 7;
        float acc = 0.f;
        for (int n = beg + h; n < end; n += 2)
            acc += bf2f(agg16[(size_t)n * 128 + col]);
        sPair[tid] = acc;
    }
    __syncthreads();
    if (tid < 128) sIn[tid] = sPair[tid] + sPair[tid + 128];
    else if (tid < 131) sIn[tid] = fg[(size_t)g * 3 + (tid - 128)];
    else if (tid == 131) sIn[131] = (float)(end - beg);
    else if (tid < 136) sIn[tid] = 0.f;
    __syncthreads();

    // phase 1: y1[tid] via 17x bf16x8 weight loads (contiguous row) + float4 LDS reads
    {
        float acc = L1b[tid];
        const unsigned short* wrow = W1cT + tid * 136;
        #pragma unroll
        for (int c = 0; c < 17; ++c) {
            bf16x8 w8 = *reinterpret_cast<const bf16x8*>(wrow + c * 8);
            const unsigned short* wu = reinterpret_cast<const unsigned short*>(&w8);
            const float* ip = &sIn[c * 8];
            float4 a0 = *reinterpret_cast<const float4*>(ip);
            float4 a1 = *reinterpret_cast<const float4*>(ip + 4);
            acc += a0.x * bf2f(wu[0]) + a0.y * bf2f(wu[1])
                 + a0.z * bf2f(wu[2]) + a0.w * bf2f(wu[3])
                 + a1.x * bf2f(wu[4]) + a1.y * bf2f(wu[5])
                 + a1.z * bf2f(wu[6]) + a1.w * bf2f(wu[7]);
        }
        sY1[tid] = selu_f(acc);
    }
    __syncthreads();

    // phase 2: y2[o] (k split over 2 threads), vectorized weight row
    {
        int o = tid & 127, h = tid >> 7, k0 = h * 128;
        float acc = 0.f;
        const unsigned short* wrow = L2wT + o * 256 + k0;
        #pragma unroll
        for (int c = 0; c < 16; ++c) {
            bf16x8 w8 = *reinterpret_cast<const bf16x8*>(wrow + c * 8);
            const unsigned short* wu = reinterpret_cast<const unsigned short*>(&w8);
            const float* ip = &sY1[k0 + c * 8];
            float4 a0 = *reinterpret_cast<const float4*>(ip);
            float4 a1 = *reinterpret_cast<const float4*>(ip + 4);
            acc += a0.x * bf2f(wu[0]) + a0.y * bf2f(wu[1])
                 + a0.z * bf2f(wu[2]) + a0.w * bf2f(wu[3])
                 + a1.x * bf2f(wu[4]) + a1.y * bf2f(wu[5])
                 + a1.z * bf2f(wu[6]) + a1.w * bf2f(wu[7]);
        }
        sPair[tid] = acc;
    }
    __syncthreads();
    if (tid < 128) {
        float y2 = selu_f(sPair[tid] + sPair[tid + 128] + L2b[tid]) * L3w[tid];
        #pragma unroll
        for (int off = 32; off > 0; off >>= 1)
            y2 += __shfl_down(y2, off, 64);
        if ((tid & 63) == 0) sRed[tid >> 6] = y2;
    }
    __syncthreads();
    if (tid == 0) out[g] = sRed[0] + sRed[1] + L3b[0];
}

extern "C" void kernel_launch(void* const* d_in, const int* in_sizes, int n_in,
                              void* d_out, int out_size, void* d_ws, size_t ws_size,
                              hipStream_t stream) {
    const float* feats_node  = (const float*)d_in[0];
    const float* feats_graph = (const float*)d_in[1];
    const int*   src         = (const int*)d_in[2];
    const int*   dst         = (const int*)d_in[3];
    const int*   node2graph  = (const int*)d_in[4];
    const float* W1 = (const float*)d_in[5];
    const float* b1 = (const float*)d_in[6];
    const float* W2 = (const float*)d_in[7];
    const float* b2 = (const float*)d_in[8];
    const float* W3 = (const float*)d_in[9];
    const float* b3 = (const float*)d_in[10];
    const float* L1w = (const float*)d_in[11];
    const float* L1b = (const float*)d_in[12];
    const float* L2w = (const float*)d_in[13];
    const float* L2b = (const float*)d_in[14];
    const float* L3w = (const float*)d_in[15];
    const float* L3b = (const float*)d_in[16];

    const int N = in_sizes[0] / 64;
    const int G = in_sizes[1] / 3;
    const int E = in_sizes[2];
    const int NBKT = (N + 255) >> 8;
    const int nmat = NBKT * NBLK;
    const int nscan = 2 * nmat;                      // cntD|cntS concatenated
    const int NBsc = (nscan + SCAN_B - 1) / SCAN_B;  // <=512 required by scan_apply2

    // ---- workspace layout ----
    int* iws = (int*)d_ws;
    int* deg_in_i  = iws;                      // N
    int* row_start = deg_in_i + N;             // N
    int* bsums     = row_start + N;            // 512
    int* cntD      = bsums + 512;              // nmat  (cntS must follow contiguously)
    int* cntS      = cntD + nmat;              // nmat
    int* csr_src   = cntS + nmat;              // E

    float* norm_out = (float*)(csr_src + E);   // N

    unsigned short* feats16 = (unsigned short*)(norm_out + N);    // [N][64]
    unsigned short* x16     = feats16 + (size_t)N * 64;           // [N][128]
    unsigned short* agg16   = x16 + (size_t)N * 128;              // [N][128]
    unsigned short* Wt1     = agg16 + (size_t)N * 128;            // 128*64
    unsigned short* Wt2     = Wt1 + 128 * 64;                     // 128*128
    unsigned short* W1cT    = Wt2 + 128 * 128;                    // 256*136
    unsigned short* L2wT    = W1cT + 256 * 136;                   // 128*256

    // pairs/sbuf alias agg16 (first written in step 4, after bucket_build)
    unsigned* pairs = (unsigned*)(((uintptr_t)agg16 + 15) & ~(uintptr_t)15);  // E u32
    int*      sbuf  = (int*)(pairs + E);                                       // E ints
    int*      sbufm = sbuf - E;   // cntS carries +E from concatenated scan

    float* out = (float*)d_out;

    // ---- 1. merged hist + weight prep (transposed head weights) ----
    {
        const int wtotal = 128 * 64 + 128 * 128 + 128 * 256 + 3 * 256 + 256
                         + 4 * 256 + 128 * 256;
        const int wblocks = (wtotal + 255) / 256;
        hist_prep_kernel<<<NBLK + wblocks, 256, 0, stream>>>(
            src, dst, cntD, cntS, E, NBKT,
            W1, W2, W3, b3, L1w, L2w, Wt1, Wt2, W1cT, L2wT);
    }

    // ---- 2. 2-stage scan + scatter ----
    scan_block_sums<<<NBsc, 256, 0, stream>>>(cntD, bsums, nscan);
    scan_apply2<<<NBsc, 256, 0, stream>>>(cntD, bsums, cntD, nscan, NBsc);
    scatter_kernel<<<NBLK, 256, 0, stream>>>(src, dst, cntD, cntS, pairs, sbufm, E, NBKT);

    // ---- 3. fused bucket build (deg_out->norm_out + feats16 + CSR) ----
    bucket_build_kernel<<<NBKT, 256, 0, stream>>>(
        sbufm, pairs, cntD, cntS, feats_node,
        norm_out, feats16, row_start, deg_in_i, csr_src, N, E, NBKT);

    const int gemm_grid = (N + 127) / 128;

    // ---- 4. layer 1 (FIN=64) ----
    csr_agg_kernel<8, 64><<<(N + 31) / 32, 256, 0, stream>>>(
        feats16, row_start, deg_in_i, csr_src, agg16, N);
    gemm_mfma_kernel<64, true, true><<<gemm_grid, 256, 0, stream>>>(
        agg16, Wt1, b1, norm_out, x16, N);

    // ---- 5. layer 2 (FIN=128) ----
    csr_agg_kernel<16, 128><<<(N + 15) / 16, 256, 0, stream>>>(
        x16, row_start, deg_in_i, csr_src, agg16, N);
    gemm_mfma_kernel<128, true, true><<<gemm_grid, 256, 0, stream>>>(
        agg16, Wt2, b2, norm_out, x16, N);

    // ---- 6. layer 3: aggregation only (W3 folded into head weights) ----
    csr_agg_kernel<16, 128><<<(N + 15) / 16, 256, 0, stream>>>(
        x16, row_start, deg_in_i, csr_src, agg16, N);

    // ---- 7. fused head: readout + 3-layer MLP, one block per graph ----
    head_kernel<<<G, 256, 0, stream>>>(
        agg16, node2graph, feats_graph, W1cT, L1b, L2wT, L2b, L3w, L3b, out, N, G);
}

// Round 21
// 340.343 us; speedup vs baseline: 1.1119x; 1.1119x over previous
//
#include <hip/hip_runtime.h>
#include <math.h>

#define SELU_ALPHA 1.6732632423543772f
#define SELU_SCALE 1.0507009873554805f

#define NBLK 512          // partition blocks (E divides exactly: 512*3125)
#define MAXBKT 512        // static LDS sizing; actual NBKT = ceil(N/256)

typedef __attribute__((ext_vector_type(8))) short bf16x8;
typedef __attribute__((ext_vector_type(4))) float f32x4;

__device__ __forceinline__ float selu_f(float x) {
    return SELU_SCALE * (x > 0.f ? x : SELU_ALPHA * expm1f(x));
}

__device__ __forceinline__ float bf2f(unsigned short u) {
    return __uint_as_float(((unsigned)u) << 16);
}
__device__ __forceinline__ unsigned short f2bf(float f) {
    unsigned u = __float_as_uint(f);
    unsigned r = (u + 0x7fffu + ((u >> 16) & 1u)) >> 16;
    return (unsigned short)r;
}

// ---- scan stage 1 ----
#define SCAN_B 1024

__global__ __launch_bounds__(256) void scan_block_sums(const int* __restrict__ in,
                                                       int* __restrict__ bsums, int n) {
    __shared__ int s[256];
    int b = blockIdx.x, t = threadIdx.x;
    int base = b * SCAN_B;
    int sum = 0;
    for (int i = t; i < SCAN_B; i += 256) {
        int idx = base + i;
        sum += (idx < n) ? in[idx] : 0;
    }
    s[t] = sum; __syncthreads();
    for (int off = 128; off > 0; off >>= 1) {
        if (t < off) s[t] += s[t + off];
        __syncthreads();
    }
    if (t == 0) bsums[b] = s[0];
}

// ---- scan stage 2 (fused bsums-scan + apply), in-place safe ----
__global__ __launch_bounds__(256) void scan_apply2(const int* __restrict__ in,
                                                   const int* __restrict__ bsums,
                                                   int* __restrict__ out, int n, int nb) {
    __shared__ int sb[512];
    __shared__ int s[256];
    __shared__ int blockoff;
    int b = blockIdx.x, t = threadIdx.x;

    int orig0 = (t < nb) ? bsums[t] : 0;
    int orig1 = (t + 256 < nb) ? bsums[t + 256] : 0;
    sb[t] = orig0; sb[t + 256] = orig1;
    __syncthreads();
    for (int off = 1; off < 512; off <<= 1) {
        int v0 = (t >= off) ? sb[t - off] : 0;
        int v1 = (t + 256 >= off) ? sb[t + 256 - off] : 0;
        __syncthreads();
        sb[t] += v0; sb[t + 256] += v1;
        __syncthreads();
    }
    if (t == (b & 255)) {
        bool hi = b >= 256;
        int incl = hi ? sb[t + 256] : sb[t];
        int orig = hi ? orig1 : orig0;
        blockoff = incl - orig;
    }
    __syncthreads();

    int idx0 = b * SCAN_B + t * 4;
    int v[4]; int tsum = 0;
    #pragma unroll
    for (int k = 0; k < 4; ++k) {
        int idx = idx0 + k;
        v[k] = (idx < n) ? in[idx] : 0;
        tsum += v[k];
    }
    s[t] = tsum; __syncthreads();
    for (int off = 1; off < 256; off <<= 1) {
        int x = (t >= off) ? s[t - off] : 0;
        __syncthreads();
        s[t] += x;
        __syncthreads();
    }
    int run = s[t] - tsum + blockoff;
    #pragma unroll
    for (int k = 0; k < 4; ++k) {
        int idx = idx0 + k;
        if (idx < n) out[idx] = run;
        run += v[k];
    }
}

// ---- K1 (merged): blocks [0,NBLK) = coarse histograms; rest = weight prep incl.
//      folded layer-3 weights: W1c = [W3@L1wA ; L1w rows 128-130 ; b3@L1wA] ----
__global__ __launch_bounds__(256) void hist_prep_kernel(
        const int* __restrict__ src, const int* __restrict__ dst,
        int* __restrict__ cntD, int* __restrict__ cntS, int E, int nbkt,
        const float* __restrict__ W1, const float* __restrict__ W2,
        const float* __restrict__ W3, const float* __restrict__ b3,
        const float* __restrict__ L1w, const float* __restrict__ L2w,
        unsigned short* __restrict__ Wt1, unsigned short* __restrict__ Wt2,
        unsigned short* __restrict__ W1c, unsigned short* __restrict__ L2w16) {
    if (blockIdx.x >= NBLK) {
        const int s0 = 128 * 64;        // Wt1
        const int s1 = 128 * 128;       // Wt2
        const int s2 = 128 * 256;       // M = W3 @ L1wA
        const int s3 = 3 * 256;         // W1c rows 128-130
        const int s4 = 256;             // c3 = b3 @ L1wA
        const int s5 = 256 * 128 / 4;   // L2w16 (vec4)
        int i = (blockIdx.x - NBLK) * 256 + threadIdx.x;
        if (i < s0) { int col = i / 64, k = i % 64; Wt1[i] = f2bf(W1[k * 128 + col]); return; }
        i -= s0;
        if (i < s1) { int col = i / 128, k = i % 128; Wt2[i] = f2bf(W2[k * 128 + col]); return; }
        i -= s1;
        if (i < s2) {
            int k = i >> 8, o = i & 255;
            float acc = 0.f;
            #pragma unroll 8
            for (int m = 0; m < 128; ++m)
                acc += W3[k * 128 + m] * L1w[m * 256 + o];
            W1c[k * 256 + o] = f2bf(acc);
            return;
        }
        i -= s2;
        if (i < s3) {
            int r = i >> 8, o = i & 255;
            W1c[(128 + r) * 256 + o] = f2bf(L1w[(128 + r) * 256 + o]);
            return;
        }
        i -= s3;
        if (i < s4) {
            int o = i;
            float acc = 0.f;
            #pragma unroll 8
            for (int m = 0; m < 128; ++m)
                acc += b3[m] * L1w[m * 256 + o];
            W1c[131 * 256 + o] = f2bf(acc);
            return;
        }
        i -= s4;
        if (i < s5) {
            float4 v = reinterpret_cast<const float4*>(L2w)[i];
            unsigned short o[4] = { f2bf(v.x), f2bf(v.y), f2bf(v.z), f2bf(v.w) };
            reinterpret_cast<uint2*>(L2w16)[i] = *reinterpret_cast<uint2*>(o);
        }
        return;
    }
    __shared__ int hD[MAXBKT];
    __shared__ int hS[MAXBKT];
    int bb = blockIdx.x, t = threadIdx.x;
    for (int k = t; k < MAXBKT; k += 256) { hD[k] = 0; hS[k] = 0; }
    __syncthreads();
    int chunk = E / NBLK;
    int beg = bb * chunk, end = beg + chunk;
    for (int i = beg + t; i < end; i += 256) {
        atomicAdd(&hD[((unsigned)dst[i]) >> 8], 1);
        atomicAdd(&hS[((unsigned)src[i]) >> 8], 1);
    }
    __syncthreads();
    for (int k = t; k < nbkt; k += 256) {
        cntD[k * NBLK + bb] = hD[k];
        cntS[k * NBLK + bb] = hS[k];
    }
}

// ---- K2: scatter. pairs packed u32: src | (dst&255)<<24 (needs N < 2^24). ----
__global__ __launch_bounds__(256) void scatter_kernel(
        const int* __restrict__ src, const int* __restrict__ dst,
        const int* __restrict__ cntD, const int* __restrict__ cntS,
        unsigned* __restrict__ pairs, int* __restrict__ sbufm, int E, int nbkt) {
    __shared__ int cD[MAXBKT];
    __shared__ int cS[MAXBKT];
    int bb = blockIdx.x, t = threadIdx.x;
    for (int k = t; k < nbkt; k += 256) {
        cD[k] = cntD[k * NBLK + bb];
        cS[k] = cntS[k * NBLK + bb];
    }
    __syncthreads();
    int chunk = E / NBLK;
    int beg = bb * chunk, end = beg + chunk;
    for (int i = beg + t; i < end; i += 256) {
        unsigned s = (unsigned)src[i], d = (unsigned)dst[i];
        int pD = atomicAdd(&cD[d >> 8], 1);
        pairs[pD] = s | ((d & 255u) << 24);
        int pS = atomicAdd(&cS[s >> 8], 1);
        sbufm[pS] = (int)s;
    }
}

// ---- K3: fused bucket build + feature conversion ----
__global__ __launch_bounds__(256) void bucket_build_kernel(
        const int* __restrict__ sbufm, const unsigned* __restrict__ pairs,
        const int* __restrict__ cntD, const int* __restrict__ cntS,
        const float* __restrict__ feats,
        float* __restrict__ norm_out, unsigned short* __restrict__ feats16,
        int* __restrict__ row_start, int* __restrict__ deg_in,
        int* __restrict__ csr_src, int N, int E, int nbkt) {
    __shared__ int hist[256];
    __shared__ int sc[256];
    __shared__ int cur[256];
    __shared__ float nrm[256];
    int b = blockIdx.x, t = threadIdx.x;
    int node = (b << 8) + t;
    int node0 = b << 8;

    // part 1: deg_out histogram from src-bucket values (+E offset indices)
    {
        int base = cntS[b * NBLK];
        int end = (b + 1 < nbkt) ? cntS[(b + 1) * NBLK] : 2 * E;
        hist[t] = 0; __syncthreads();
        for (int i = base + t; i < end; i += 256)
            atomicAdd(&hist[sbufm[i] & 255], 1);
        __syncthreads();
        float no = 1.f / sqrtf(fmaxf((float)hist[t], 1.f));
        nrm[t] = no;
        if (node < N) norm_out[node] = no;
        __syncthreads();
    }

    // part 1b: convert this node range's features to bf16, prescaled by norm_out
    {
        int cnt = min(256, N - node0);
        for (int i = t; i < cnt * 8; i += 256) {
            int nl = i >> 3, c = i & 7;
            float no = nrm[nl];
            const float* fp = feats + (size_t)(node0 + nl) * 64 + c * 8;
            float4 a = *reinterpret_cast<const float4*>(fp);
            float4 bv = *reinterpret_cast<const float4*>(fp + 4);
            unsigned short o[8] = { f2bf(a.x * no), f2bf(a.y * no), f2bf(a.z * no), f2bf(a.w * no),
                                    f2bf(bv.x * no), f2bf(bv.y * no), f2bf(bv.z * no), f2bf(bv.w * no) };
            *reinterpret_cast<float4*>(feats16 + (size_t)(node0 + nl) * 64 + c * 8) =
                *reinterpret_cast<float4*>(o);
        }
        __syncthreads();
    }

    // part 2: CSR build from packed dst-bucket pairs
    {
        int base = cntD[b * NBLK];
        int end = (b + 1 < nbkt) ? cntD[(b + 1) * NBLK] : E;
        hist[t] = 0; __syncthreads();
        for (int i = base + t; i < end; i += 256)
            atomicAdd(&hist[(pairs[i] >> 24) & 255], 1);
        __syncthreads();
        int v = hist[t];
        sc[t] = v; __syncthreads();
        for (int off = 1; off < 256; off <<= 1) {
            int x = (t >= off) ? sc[t - off] : 0;
            __syncthreads();
            sc[t] += x;
            __syncthreads();
        }
        int ex = sc[t] - v;
        cur[t] = base + ex;
        if (node < N) { row_start[node] = base + ex; deg_in[node] = v; }
        __syncthreads();
        for (int i = base + t; i < end; i += 256) {
            unsigned p = pairs[i];
            int pos = atomicAdd(&cur[(p >> 24) & 255], 1);
            csr_src[pos] = (int)(p & 0xFFFFFFu);
        }
    }
}

// ---- gather-aggregate with shuffle-broadcast + next-chunk index prefetch ----
template<int TPG, int FIN>   // TPG = FIN/8
__global__ __launch_bounds__(256) void csr_agg_kernel(
        const unsigned short* __restrict__ x, const int* __restrict__ row_start,
        const int* __restrict__ deg_in, const int* __restrict__ csr_src,
        unsigned short* __restrict__ agg, int N) {
    const int GPB = 256 / TPG;
    int g = threadIdx.x / TPG;
    int j = threadIdx.x % TPG;
    int n = blockIdx.x * GPB + g;
    if (n >= N) return;
    const int lane = threadIdx.x & 63;
    const int gbase = lane & ~(TPG - 1);
    int beg = row_start[n];
    int dg = deg_in[n];
    int end = beg + dg;
    float nin = 1.f / sqrtf(fmaxf((float)dg, 1.f));
    float acc[8] = {0.f, 0.f, 0.f, 0.f, 0.f, 0.f, 0.f, 0.f};
    int myIdx = (beg + j < end) ? csr_src[beg + j] : 0;
    for (int c = beg; c < end; c += TPG) {
        int cnt = end - c;
        int nxtIdx = (c + TPG + j < end) ? csr_src[c + TPG + j] : 0;
        float4 v[TPG];
        #pragma unroll
        for (int t = 0; t < TPG; ++t) {
            if (t < cnt) {
                int s = __shfl(myIdx, gbase + t, 64);
                v[t] = *reinterpret_cast<const float4*>(&x[(size_t)s * FIN + j * 8]);
            }
        }
        #pragma unroll
        for (int t = 0; t < TPG; ++t) {
            if (t < cnt) {
                const unsigned short* u = reinterpret_cast<const unsigned short*>(&v[t]);
                #pragma unroll
                for (int k = 0; k < 8; ++k) acc[k] += bf2f(u[k]);
            }
        }
        myIdx = nxtIdx;
    }
    unsigned short ov[8];
    #pragma unroll
    for (int k = 0; k < 8; ++k) ov[k] = f2bf(acc[k] * nin);
    *reinterpret_cast<float4*>(&agg[(size_t)n * FIN + j * 8]) = *reinterpret_cast<float4*>(ov);
}

// ---- MFMA node GEMM: W in LDS only (4 blocks/CU), A streamed from global ----
template<int FIN, bool SELU, bool SCALE_OUT>
__global__ __launch_bounds__(256, 4) void gemm_mfma_kernel(
        const unsigned short* __restrict__ agg16,  // [N][FIN] bf16
        const unsigned short* __restrict__ Wt,     // [128][FIN] bf16
        const float* __restrict__ b,
        const float* __restrict__ norm_out,
        unsigned short* __restrict__ out,          // [N][128] bf16
        int N) {
    const int PAD = 8;
    const int LDW = FIN + PAD;
    const int CH = FIN / 8;
    __shared__ unsigned short sW[128 * LDW];
    const int tid = threadIdx.x;
    const int wave = tid >> 6, lane = tid & 63;
    const int wr = (wave >> 1) * 64;
    const int wc = (wave & 1) * 64;
    const int n0 = blockIdx.x * 128;

    for (int i = tid; i < 128 * CH; i += 256) {
        int col = i / CH, kc = i % CH;
        *reinterpret_cast<float4*>(&sW[col * LDW + kc * 8]) =
            *reinterpret_cast<const float4*>(&Wt[col * FIN + kc * 8]);
    }
    __syncthreads();

    const int l16 = lane & 15;
    const int lk = (lane >> 4) * 8;
    const bf16x8 zero8 = (bf16x8){0,0,0,0,0,0,0,0};
    f32x4 acc[4][4];
    #pragma unroll
    for (int mi = 0; mi < 4; ++mi)
        #pragma unroll
        for (int ci = 0; ci < 4; ++ci)
            acc[mi][ci] = (f32x4){0.f, 0.f, 0.f, 0.f};

    #pragma unroll
    for (int k0 = 0; k0 < FIN; k0 += 32) {
        bf16x8 a[4], w[4];
        #pragma unroll
        for (int mi = 0; mi < 4; ++mi) {
            int n = n0 + wr + mi * 16 + l16;
            a[mi] = (n < N)
                ? *reinterpret_cast<const bf16x8*>(&agg16[(size_t)n * FIN + k0 + lk])
                : zero8;
        }
        #pragma unroll
        for (int ci = 0; ci < 4; ++ci)
            w[ci] = *reinterpret_cast<const bf16x8*>(&sW[(wc + ci * 16 + l16) * LDW + k0 + lk]);
        #pragma unroll
        for (int mi = 0; mi < 4; ++mi)
            #pragma unroll
            for (int ci = 0; ci < 4; ++ci)
                acc[mi][ci] = __builtin_amdgcn_mfma_f32_16x16x32_bf16(
                    a[mi], w[ci], acc[mi][ci], 0, 0, 0);
    }

    const int rbase = (lane >> 4) * 4;
    #pragma unroll
    for (int ci = 0; ci < 4; ++ci) {
        int col = wc + ci * 16 + l16;
        float bias = b[col];
        #pragma unroll
        for (int mi = 0; mi < 4; ++mi) {
            #pragma unroll
            for (int r = 0; r < 4; ++r) {
                int n = n0 + wr + mi * 16 + rbase + r;
                if (n < N) {
                    float v = acc[mi][ci][r] + bias;
                    if (SELU) v = selu_f(v);
                    if (SCALE_OUT) v *= norm_out[n];
                    out[(size_t)n * 128 + col] = f2bf(v);
                }
            }
        }
    }
}

// ---- FUSED head: 4 graphs per block; coalesced per-k weight loads amortized
//      across 4 graphs (1 load + cvt feeds 4 FMAs). ----
__global__ __launch_bounds__(256) void head_kernel(
        const unsigned short* __restrict__ agg16,  // [N][128] bf16
        const int* __restrict__ n2g,               // [N] sorted
        const float* __restrict__ fg,              // [G][3]
        const unsigned short* __restrict__ W1c,    // [132][256] bf16
        const float* __restrict__ L1b,
        const unsigned short* __restrict__ L2w16,  // [256][128] bf16
        const float* __restrict__ L2b,
        const float* __restrict__ L3w, const float* __restrict__ L3b,
        float* __restrict__ out, int N, int G) {
    __shared__ float sIn[4][132];
    __shared__ float sY1[4][256];
    __shared__ float sPair[256];
    __shared__ float sP2[4][256];
    __shared__ float sRed[4][2];
    int g0 = blockIdx.x * 4;
    int tid = threadIdx.x;

    // phase 0: readout, one graph at a time (2 threads/col)
    for (int gg = 0; gg < 4; ++gg) {
        int g = g0 + gg;
        int beg = 0, end = 0;
        if (g < G) {
            int lo = 0, hi = N;
            while (lo < hi) { int m = (lo + hi) >> 1; if (n2g[m] < g) lo = m + 1; else hi = m; }
            beg = lo;
            lo = beg; hi = N;
            while (lo < hi) { int m = (lo + hi) >> 1; if (n2g[m] < g + 1) lo = m + 1; else hi = m; }
            end = lo;
        }
        int col = tid & 127, h = tid >> 7;
        float acc = 0.f;
        for (int n = beg + h; n < end; n += 2)
            acc += bf2f(agg16[(size_t)n * 128 + col]);
        sPair[tid] = acc;
        __syncthreads();
        if (tid < 128) sIn[gg][tid] = sPair[tid] + sPair[tid + 128];
        else if (tid < 131) sIn[gg][tid] = (g < G) ? fg[(size_t)g * 3 + (tid - 128)] : 0.f;
        else if (tid == 131) sIn[gg][131] = (float)(end - beg);
        __syncthreads();
    }

    // phase 1: y1 for 4 graphs; one coalesced weight load per k feeds 4 FMAs
    {
        float b1v = L1b[tid];
        float a0 = b1v, a1 = b1v, a2 = b1v, a3 = b1v;
        #pragma unroll 4
        for (int k = 0; k < 132; ++k) {
            float w = bf2f(W1c[k * 256 + tid]);
            a0 += sIn[0][k] * w;
            a1 += sIn[1][k] * w;
            a2 += sIn[2][k] * w;
            a3 += sIn[3][k] * w;
        }
        sY1[0][tid] = selu_f(a0);
        sY1[1][tid] = selu_f(a1);
        sY1[2][tid] = selu_f(a2);
        sY1[3][tid] = selu_f(a3);
    }
    __syncthreads();

    // phase 2: y2 (k split over 2 threads), amortized over 4 graphs
    {
        int o = tid & 127, h = tid >> 7, k0 = h * 128;
        float a0 = 0.f, a1 = 0.f, a2 = 0.f, a3 = 0.f;
        #pragma unroll 4
        for (int k = 0; k < 128; ++k) {
            float w = bf2f(L2w16[(k0 + k) * 128 + o]);
            a0 += sY1[0][k0 + k] * w;
            a1 += sY1[1][k0 + k] * w;
            a2 += sY1[2][k0 + k] * w;
            a3 += sY1[3][k0 + k] * w;
        }
        sP2[0][tid] = a0; sP2[1][tid] = a1; sP2[2][tid] = a2; sP2[3][tid] = a3;
    }
    __syncthreads();
    if (tid < 128) {
        float b2v = L2b[tid];
        float w3 = L3w[tid];
        #pragma unroll
        for (int gg = 0; gg < 4; ++gg) {
            float y2 = selu_f(sP2[gg][tid] + sP2[gg][tid + 128] + b2v) * w3;
            #pragma unroll
            for (int off = 32; off > 0; off >>= 1)
                y2 += __shfl_down(y2, off, 64);
            if ((tid & 63) == 0) sRed[gg][tid >> 6] = y2;
        }
    }
    __syncthreads();
    if (tid < 4) {
        int g = g0 + tid;
        if (g < G) out[g] = sRed[tid][0] + sRed[tid][1] + L3b[0];
    }
}

extern "C" void kernel_launch(void* const* d_in, const int* in_sizes, int n_in,
                              void* d_out, int out_size, void* d_ws, size_t ws_size,
                              hipStream_t stream) {
    const float* feats_node  = (const float*)d_in[0];
    const float* feats_graph = (const float*)d_in[1];
    const int*   src         = (const int*)d_in[2];
    const int*   dst         = (const int*)d_in[3];
    const int*   node2graph  = (const int*)d_in[4];
    const float* W1 = (const float*)d_in[5];
    const float* b1 = (const float*)d_in[6];
    const float* W2 = (const float*)d_in[7];
    const float* b2 = (const float*)d_in[8];
    const float* W3 = (const float*)d_in[9];
    const float* b3 = (const float*)d_in[10];
    const float* L1w = (const float*)d_in[11];
    const float* L1b = (const float*)d_in[12];
    const float* L2w = (const float*)d_in[13];
    const float* L2b = (const float*)d_in[14];
    const float* L3w = (const float*)d_in[15];
    const float* L3b = (const float*)d_in[16];

    const int N = in_sizes[0] / 64;
    const int G = in_sizes[1] / 3;
    const int E = in_sizes[2];
    const int NBKT = (N + 255) >> 8;
    const int nmat = NBKT * NBLK;
    const int nscan = 2 * nmat;                      // cntD|cntS concatenated
    const int NBsc = (nscan + SCAN_B - 1) / SCAN_B;  // <=512 required by scan_apply2

    // ---- workspace layout ----
    int* iws = (int*)d_ws;
    int* deg_in_i  = iws;                      // N
    int* row_start = deg_in_i + N;             // N
    int* bsums     = row_start + N;            // 512
    int* cntD      = bsums + 512;              // nmat  (cntS must follow contiguously)
    int* cntS      = cntD + nmat;              // nmat
    int* csr_src   = cntS + nmat;              // E

    float* norm_out = (float*)(csr_src + E);   // N

    unsigned short* feats16 = (unsigned short*)(norm_out + N);    // [N][64]
    unsigned short* x16     = feats16 + (size_t)N * 64;           // [N][128]
    unsigned short* agg16   = x16 + (size_t)N * 128;              // [N][128]
    unsigned short* Wt1     = agg16 + (size_t)N * 128;            // 128*64
    unsigned short* Wt2     = Wt1 + 128 * 64;                     // 128*128
    unsigned short* W1c     = Wt2 + 128 * 128;                    // 132*256
    unsigned short* L2w16   = W1c + 132 * 256;                    // 256*128

    // pairs/sbuf alias agg16 (first written in step 4, after bucket_build)
    unsigned* pairs = (unsigned*)(((uintptr_t)agg16 + 15) & ~(uintptr_t)15);  // E u32
    int*      sbuf  = (int*)(pairs + E);                                       // E ints
    int*      sbufm = sbuf - E;   // cntS carries +E from concatenated scan

    float* out = (float*)d_out;

    // ---- 1. merged hist + weight prep (incl. folded layer-3 weights) ----
    {
        const int wtotal = 128 * 64 + 128 * 128 + 128 * 256 + 3 * 256 + 256 + 256 * 128 / 4;
        const int wblocks = (wtotal + 255) / 256;
        hist_prep_kernel<<<NBLK + wblocks, 256, 0, stream>>>(
            src, dst, cntD, cntS, E, NBKT,
            W1, W2, W3, b3, L1w, L2w, Wt1, Wt2, W1c, L2w16);
    }

    // ---- 2. 2-stage scan + scatter ----
    scan_block_sums<<<NBsc, 256, 0, stream>>>(cntD, bsums, nscan);
    scan_apply2<<<NBsc, 256, 0, stream>>>(cntD, bsums, cntD, nscan, NBsc);
    scatter_kernel<<<NBLK, 256, 0, stream>>>(src, dst, cntD, cntS, pairs, sbufm, E, NBKT);

    // ---- 3. fused bucket build (deg_out->norm_out + feats16 + CSR) ----
    bucket_build_kernel<<<NBKT, 256, 0, stream>>>(
        sbufm, pairs, cntD, cntS, feats_node,
        norm_out, feats16, row_start, deg_in_i, csr_src, N, E, NBKT);

    const int gemm_grid = (N + 127) / 128;

    // ---- 4. layer 1 (FIN=64) ----
    csr_agg_kernel<8, 64><<<(N + 31) / 32, 256, 0, stream>>>(
        feats16, row_start, deg_in_i, csr_src, agg16, N);
    gemm_mfma_kernel<64, true, true><<<gemm_grid, 256, 0, stream>>>(
        agg16, Wt1, b1, norm_out, x16, N);

    // ---- 5. layer 2 (FIN=128) ----
    csr_agg_kernel<16, 128><<<(N + 15) / 16, 256, 0, stream>>>(
        x16, row_start, deg_in_i, csr_src, agg16, N);
    gemm_mfma_kernel<128, true, true><<<gemm_grid, 256, 0, stream>>>(
        agg16, Wt2, b2, norm_out, x16, N);

    // ---- 6. layer 3: aggregation only (W3 folded into head weights) ----
    csr_agg_kernel<16, 128><<<(N + 15) / 16, 256, 0, stream>>>(
        x16, row_start, deg_in_i, csr_src, agg16, N);

    // ---- 7. fused head: readout + 3-layer MLP, 4 graphs per block ----
    head_kernel<<<(G + 3) / 4, 256, 0, stream>>>(
        agg16, node2graph, feats_graph, W1c, L1b, L2w16, L2b, L3w, L3b, out, N, G);
}